// Round 4
// baseline (335.824 us; speedup 1.0000x reference)
//
#include <hip/hip_runtime.h>
#include <math.h>

typedef unsigned short u16;
typedef __attribute__((ext_vector_type(8))) short short8;
typedef __attribute__((ext_vector_type(4))) float floatx4;

constexpr int BATCH = 16;
constexpr int NI = 1024;
constexpr int CE = 64;
constexpr int CI = 16;
constexpr long long NN2  = (long long)NI * NI;          // 1M
constexpr long long BCN  = (long long)BATCH * CE * NI;  // 1M
constexpr long long BNv  = (long long)BATCH * NI;       // 16K
constexpr long long BNN  = (long long)BATCH * NI * NI;  // 16M
constexpr long long S1 = (long long)CE * NI;            // 65536
constexpr long long S2 = 2 * S1;                        // 131072

__device__ __forceinline__ float lrelu01(float x) { return x > 0.f ? x : 0.01f * x; }

__device__ __forceinline__ u16 f2bf(float f) {
  unsigned u = __builtin_bit_cast(unsigned, f);
  return (u16)((u + 0x7fffu + ((u >> 16) & 1u)) >> 16);  // RNE
}
__device__ __forceinline__ float bf2f(u16 h) {
  unsigned u = ((unsigned)h) << 16;
  return __builtin_bit_cast(float, u);
}
// monotonic uint key for float atomicMax (memset-0 init is safe: keys of real floats > 0)
__device__ __forceinline__ unsigned fkey(float f) {
  unsigned u = __builtin_bit_cast(unsigned, f);
  return (u & 0x80000000u) ? ~u : (u | 0x80000000u);
}
__device__ __forceinline__ float funkey(unsigned k) {
  unsigned u = (k & 0x80000000u) ? (k & 0x7fffffffu) : ~k;
  return __builtin_bit_cast(float, u);
}

// ================= MFMA TN GEMM: C[r][m] = sum_k A[r][k] * Bt[m][k] ==============
// A, Bt bf16 row-major K-contiguous. BK=64, XOR-swizzled 16B chunks in LDS.
// 4 waves 2x2; wave tile (BM/2)x(BN/2); 16x16x32 MFMAs.
// MODE: 0 +colbias fp32 | 1 rowscale+relu bf16 | 2 dual +colbias + sq-atomics |
//       3 gram exp epilogue + rowsum atomics | 4 Abig scatter w/ Z-div | 6 bf16 |
//       7 W-half (XCD z-swizzle, rank-1 epilogue) | 8 G12-half (XCD bx-swizzle, accum)
template<int BM, int BN, int MODE>
__global__ __launch_bounds__(256) void mgemm(
    const u16* __restrict__ Ag, const u16* __restrict__ B1g, const u16* __restrict__ B2g,
    int K1, int K, int lda, int ldb, long long bsA, long long bsB1,
    float* __restrict__ Cf, u16* __restrict__ Cb, int ldc, long long bsC,
    const float* __restrict__ aux1, const float* __restrict__ aux2,
    const float* __restrict__ aux3, const float* __restrict__ aux4,
    float* __restrict__ Zout)
{
  constexpr int RM = BM / 2, RN = BN / 2, MI = RM / 16, NJ = RN / 16;
  __shared__ __align__(16) u16 As[BM * 64];
  __shared__ __align__(16) u16 Bs[BN * 64];
  int z, n0, r0;
  if constexpr (MODE == 7) {
    // cluster all 32 blocks of batch z on XCD z&7 (bigW L2 reuse)
    const int id = blockIdx.x;
    const int q2 = id >> 3;
    z = (id & 7) + 8 * (q2 & 1);
    const int rr = q2 >> 1;          // 0..31
    n0 = (rr & 15) * BN;
    r0 = (rr >> 4) * BM;
  } else if constexpr (MODE == 8) {
    // cluster all 32 blocks of column-tile bx on XCD bx&7 (G12 L2 reuse)
    const int id = blockIdx.x;
    n0 = (id & 15) * BN;
    const int t2 = id >> 4;          // 0..31
    z = t2 & 15;
    r0 = (t2 >> 4) * BM;
  } else {
    z = blockIdx.z; n0 = blockIdx.x * BN; r0 = blockIdx.y * BM;
  }
  const u16* Ab = Ag + (long long)z * bsA + (long long)r0 * lda;
  const u16* Bb1 = B1g + (long long)z * bsB1 + (long long)n0 * ldb;
  const int tid = threadIdx.x;
  const int lane = tid & 63;
  const int wid = tid >> 6;
  const int wr = wid >> 1, wc = wid & 1;
  const int q = lane >> 4, mlow = lane & 15;

  floatx4 acc[MI][NJ] = {};

  for (int k0 = 0; k0 < K; k0 += 64) {
    const u16* Asrc = Ab + k0;
    const u16* Bsrc = (k0 < K1) ? (Bb1 + k0)
                                : (B2g + (long long)n0 * ldb + (k0 - K1));
#pragma unroll
    for (int s = 0; s < (BM * 8) / 256; s++) {
      int cid = tid + s * 256;
      int r = cid >> 3, craw = cid & 7;
      uint4 v = *(const uint4*)(Asrc + (long long)r * lda + craw * 8);
      *(uint4*)&As[(r * 8 + (craw ^ (r & 7))) * 8] = v;
    }
#pragma unroll
    for (int s = 0; s < (BN * 8) / 256; s++) {
      int cid = tid + s * 256;
      int r = cid >> 3, craw = cid & 7;
      uint4 v = *(const uint4*)(Bsrc + (long long)r * ldb + craw * 8);
      *(uint4*)&Bs[(r * 8 + (craw ^ (r & 7))) * 8] = v;
    }
    __syncthreads();
#pragma unroll
    for (int kh = 0; kh < 2; kh++) {
      const int kc = kh * 4 + q;
      short8 afr[MI], bfr[NJ];
#pragma unroll
      for (int i = 0; i < MI; i++) {
        int row = wr * RM + i * 16 + mlow;
        afr[i] = *(const short8*)&As[(row * 8 + (kc ^ (row & 7))) * 8];
      }
#pragma unroll
      for (int j = 0; j < NJ; j++) {
        int row = wc * RN + j * 16 + mlow;
        bfr[j] = *(const short8*)&Bs[(row * 8 + (kc ^ (row & 7))) * 8];
      }
#pragma unroll
      for (int i = 0; i < MI; i++)
#pragma unroll
        for (int j = 0; j < NJ; j++)
          acc[i][j] = __builtin_amdgcn_mfma_f32_16x16x32_bf16(afr[i], bfr[j], acc[i][j], 0, 0, 0);
    }
    __syncthreads();
  }

  if constexpr (MODE == 3) {
    const float* sqb = aux1 + (long long)z * NI;
#pragma unroll
    for (int i = 0; i < MI; i++) {
#pragma unroll
      for (int rg = 0; rg < 4; rg++) {
        int r = r0 + wr * RM + i * 16 + q * 4 + rg;
        float sqi = sqb[r];
        float rsum = 0.f;
#pragma unroll
        for (int j = 0; j < NJ; j++) {
          int ncol = n0 + wc * RN + j * 16 + mlow;
          float d2 = fmaxf(sqi + sqb[ncol] - 2.f * acc[i][j][rg], 0.f);
          float w = __expf(__expf(-d2 * (1.f / 128.f)) + (r == ncol ? 1.f : 0.f) - 2.f);
          Cb[(long long)z * bsC + (long long)r * ldc + ncol] = f2bf(w);
          rsum += w;
        }
        rsum += __shfl_xor(rsum, 1);
        rsum += __shfl_xor(rsum, 2);
        rsum += __shfl_xor(rsum, 4);
        rsum += __shfl_xor(rsum, 8);
        if (mlow == 0) atomicAdd(&Zout[(long long)z * NI + r], rsum);
      }
    }
  } else if constexpr (MODE == 2) {
    // dual write + per-row sum of squares (atomics into Zout=sqv, pre-zeroed)
#pragma unroll
    for (int i = 0; i < MI; i++) {
#pragma unroll
      for (int rg = 0; rg < 4; rg++) {
        int r = r0 + wr * RM + i * 16 + q * 4 + rg;
        float sqp = 0.f;
#pragma unroll
        for (int j = 0; j < NJ; j++) {
          int ncol = n0 + wc * RN + j * 16 + mlow;
          float v = acc[i][j][rg] + aux1[ncol];
          long long ix = (long long)z * bsC + (long long)r * ldc + ncol;
          Cf[ix] = v;
          Cb[ix] = f2bf(v);
          sqp = fmaf(v, v, sqp);
        }
        sqp += __shfl_xor(sqp, 1);
        sqp += __shfl_xor(sqp, 2);
        sqp += __shfl_xor(sqp, 4);
        sqp += __shfl_xor(sqp, 8);
        if (mlow == 0) atomicAdd(&Zout[(long long)z * NI + r], sqp);
      }
    }
  } else {
#pragma unroll
    for (int i = 0; i < MI; i++) {
#pragma unroll
      for (int j = 0; j < NJ; j++) {
#pragma unroll
        for (int rg = 0; rg < 4; rg++) {
          int r = r0 + wr * RM + i * 16 + q * 4 + rg;
          int ncol = n0 + wc * RN + j * 16 + mlow;
          float v = acc[i][j][rg];
          if constexpr (MODE == 0) {
            v += aux1[ncol];
            Cf[(long long)z * bsC + (long long)r * ldc + ncol] = v;
          } else if constexpr (MODE == 1) {
            v *= aux1[(long long)z * NI + r];
            v = fmaxf(v, 0.f);
            Cb[(long long)z * bsC + (long long)r * ldc + ncol] = f2bf(v);
          } else if constexpr (MODE == 4) {
            int blk = r >> 6, oo = r & 63;
            int drow = ((blk & 1) << 6) + oo;
            if (blk < 2) v = v / aux1[(long long)z * NI + ncol];  // fold 1/Zgl
            Cb[(long long)z * bsC + (long long)drow * 2048 + (long long)(blk >> 1) * 1024 + ncol] =
                f2bf(v);
          } else if constexpr (MODE == 6) {
            Cb[(long long)z * bsC + (long long)r * ldc + ncol] = f2bf(v);
          } else if constexpr (MODE == 7) {
            v += aux3[r] * aux1[(long long)z * NI + ncol] + aux4[r] * aux2[ncol];
            Cf[(long long)z * bsC + (long long)r * ldc + ncol] = v;
          } else if constexpr (MODE == 8) {
            long long ix = (long long)z * bsC + (long long)r * ldc + ncol;
            Cf[ix] = v + Cf[ix];  // serial after MODE7 dispatch: safe accumulate
          }
        }
      }
    }
  }
}

// ---------------- lap_rowsum: dr[k][i] = rsqrt(1 + rowsum(graph[k][i])) --------------
__global__ __launch_bounds__(256) void lap_rowsum(const float* __restrict__ gd,
                                                  float* __restrict__ dr)
{
  const int ki = blockIdx.x;
  const float* row = gd + (long long)ki * NI;
  float s = 0.f;
  for (int j = threadIdx.x; j < NI; j += 256) s += row[j];
  __shared__ float red[256];
  red[threadIdx.x] = s; __syncthreads();
  for (int st = 128; st > 0; st >>= 1) {
    if (threadIdx.x < st) red[threadIdx.x] += red[threadIdx.x + st];
    __syncthreads();
  }
  if (threadIdx.x == 0) dr[ki] = rsqrtf(red[0] + 1.f);
}

// ---------------- mega_prep: blockIdx-range dispatch of all prep work ----------------
// [0,81)      prep_small: stack4/rb2ext/rl2ext/uaiw_bf
// [81,4177)   cast emb2_w -> bf16
// [4177,5201) conv_emb
// [5201,9297) g_direct (g2^T)
// [9297,10321) g_trans (g1)
// [10321,11345) cs1
__global__ __launch_bounds__(256) void mega_prep(
    const float* __restrict__ l1w, const float* __restrict__ l2w,
    const float* __restrict__ l2b, const float* __restrict__ uaiw,
    u16* __restrict__ stack4, float* __restrict__ rb2ext, float* __restrict__ rl2ext,
    u16* __restrict__ uaiw_bf,
    const float* __restrict__ emb2w, u16* __restrict__ emb2w_bf,
    const float* __restrict__ x, const float* __restrict__ ew,
    const float* __restrict__ eb, u16* __restrict__ h0a,
    const float* __restrict__ gd, const float* __restrict__ dsum,
    u16* __restrict__ g2t, u16* __restrict__ g1,
    float* __restrict__ cs1)
{
  __shared__ float sm[1088];
  const int bid = blockIdx.x;
  const int t = threadIdx.x;
  if (bid < 81) {
    const int gid = bid * 256 + t;
    if (gid < 4096) {
      stack4[gid] = f2bf(l1w[gid]);
    } else if (gid < 8192) {
      stack4[gid] = f2bf(l2w[gid - 4096]);
    } else if (gid < 12288) {
      int tt = gid - 8192, o = tt >> 6, m = tt & 63;
      float s = 0.f;
      for (int c = 0; c < 64; c++) s = fmaf(l1w[o * 64 + c], l1w[c * 64 + m], s);
      stack4[gid] = f2bf(s);
    } else if (gid < 16384) {
      int tt = gid - 12288, o = tt >> 6, m = tt & 63;
      float s = 0.f;
      for (int c = 0; c < 64; c++) s = fmaf(l2w[o * 64 + c], l2w[c * 64 + m], s);
      stack4[gid] = f2bf(s);
    } else if (gid < 16512) {
      int r = gid - 16384;
      rb2ext[r] = (r < 64) ? 0.f : l2b[r - 64];
    } else if (gid < 16640) {
      int r = gid - 16512;
      float v = 0.f;
      if (r >= 64) { int o = r - 64; for (int c = 0; c < 64; c++) v = fmaf(l2w[o * 64 + c], l2b[c], v); }
      rl2ext[r] = v;
    } else if (gid < 20736) {
      uaiw_bf[gid - 16640] = f2bf(uaiw[gid - 16640]);
    }
  } else if (bid < 4177) {
    const long long i = (long long)(bid - 81) * 256 + t;
    emb2w_bf[i] = f2bf(emb2w[i]);
  } else if (bid < 5201) {
    const int be = bid - 4177;
    const int b = be >> 6, e = be & 63;
    float* w = sm;
    if (t < CI) w[t] = ew[e * CI + t];
    __syncthreads();
    const float bias = eb[e];
    const float* xb = x + (long long)b * CI * NI;
    u16* outp = h0a + (long long)be * NI;
    for (int n = t; n < NI; n += 256) {
      float a = bias;
#pragma unroll
      for (int c = 0; c < CI; c++) a = fmaf(xb[c * NI + n], w[c], a);
      outp[n] = f2bf(lrelu01(a));
    }
  } else if (bid < 9297) {
    const long long idx = (long long)(bid - 5201) * 256 + t;
    const int m = (int)(idx >> 10), j = (int)(idx & 1023);
    const float* d = dsum + NI;
    float v = (gd[NN2 + idx] + (m == j ? 1.f : 0.f)) * d[m] * d[j];
    g2t[idx] = f2bf(v);
  } else if (bid < 10321) {
    const int sub = bid - 9297;
    const int bx = (sub & 31) * 32, by = (sub >> 5) * 32;
    const int lx = t & 31, ly = t >> 5;  // 32x8
    float* tile = sm;                    // 32x33
    for (int yy = ly; yy < 32; yy += 8)
      tile[yy * 33 + lx] = gd[(long long)(by + yy) * NI + bx + lx];
    __syncthreads();
    for (int yy = ly; yy < 32; yy += 8) {
      const int i = bx + yy, j = by + lx;
      float v = (tile[lx * 33 + yy] + (i == j ? 1.f : 0.f)) * dsum[i] * dsum[j];
      g1[(long long)i * NI + j] = f2bf(v);
    }
  } else {
    const int n = bid - 10321;
    float s = 0.f;
    for (int i = t; i < NI; i += 256) s = fmaf(gd[(long long)n * NI + i], dsum[i], s);
    float* red = sm;
    red[t] = s; __syncthreads();
    for (int st = 128; st > 0; st >>= 1) {
      if (t < st) red[t] += red[t + st];
      __syncthreads();
    }
    if (t == 0) cs1[n] = dsum[n] * (red[0] + dsum[n]);
  }
}

// cs2[m] = colsum g2; v2[m] = (cs1 @ g2)[m]
__global__ __launch_bounds__(256) void csv2_kernel(const float* __restrict__ gd1,
                                                   const float* __restrict__ d,
                                                   const float* __restrict__ cs1,
                                                   float* __restrict__ cs2,
                                                   float* __restrict__ v2)
{
  const int m = blockIdx.x;
  float s = 0.f, sv = 0.f;
  for (int n = threadIdx.x; n < NI; n += 256) {
    float g = gd1[(long long)m * NI + n] * d[n];
    s += g;
    sv = fmaf(g, cs1[n], sv);
  }
  __shared__ float r1[256], r2[256];
  r1[threadIdx.x] = s; r2[threadIdx.x] = sv; __syncthreads();
  for (int st = 128; st > 0; st >>= 1) {
    if (threadIdx.x < st) { r1[threadIdx.x] += r1[threadIdx.x + st]; r2[threadIdx.x] += r2[threadIdx.x + st]; }
    __syncthreads();
  }
  if (threadIdx.x == 0) {
    cs2[m] = d[m] * (r1[0] + d[m]);
    v2[m] = d[m] * (r2[0] + d[m] * cs1[m]);
  }
}

// hT: h[b][c][n] bf16 + s1/s2 scores + per-batch s2 max (atomicMax on uint key)
__global__ __launch_bounds__(256) void hT_kernel(const float* __restrict__ h0,
                                                 const float* __restrict__ attW,
                                                 const float* __restrict__ atta,
                                                 u16* __restrict__ hTb,
                                                 float* __restrict__ s1,
                                                 float* __restrict__ s2,
                                                 unsigned* __restrict__ s2mU)
{
  __shared__ float w[64 * 64];
  for (int t = threadIdx.x; t < 4096; t += 256) w[t] = attW[t];
  __syncthreads();
  const int b = blockIdx.y;
  const int wid = threadIdx.x >> 6, lane = threadIdx.x & 63;
  const int n0 = blockIdx.x * 16 + wid * 4;
  const float* h0b = h0 + (long long)b * S1;
  float a0 = 0, a1 = 0, a2 = 0, a3 = 0;
  for (int e = 0; e < 64; e++) {
    float4 hv = *(const float4*)(h0b + e * NI + n0);
    float we = w[e * 64 + lane];
    a0 = fmaf(hv.x, we, a0); a1 = fmaf(hv.y, we, a1);
    a2 = fmaf(hv.z, we, a2); a3 = fmaf(hv.w, we, a3);
  }
  unsigned lo = (unsigned)f2bf(a0) | ((unsigned)f2bf(a1) << 16);
  unsigned hi = (unsigned)f2bf(a2) | ((unsigned)f2bf(a3) << 16);
  uint2 pk; pk.x = lo; pk.y = hi;
  *(uint2*)(hTb + (long long)b * S1 + (long long)lane * NI + n0) = pk;
  const float p1 = atta[lane], p2 = atta[64 + lane];
  float av[4] = {a0, a1, a2, a3};
  float mx = -3.4e38f;
#pragma unroll
  for (int j = 0; j < 4; j++) {
    float v1 = av[j] * p1, v2 = av[j] * p2;
    for (int off = 1; off < 64; off <<= 1) { v1 += __shfl_xor(v1, off); v2 += __shfl_xor(v2, off); }
    if (lane == j) { s1[(long long)b * NI + n0 + j] = v1; s2[(long long)b * NI + n0 + j] = v2; }
    mx = fmaxf(mx, v2);
  }
  if (lane == 0) atomicMax(&s2mU[b], fkey(mx));
}

// p (bf16, uint2 x4 stores) = exp(lrelu(s1_i+s2_j) - rowmax); invZatt = 1/rowsum
__global__ __launch_bounds__(256) void att_p(const float* __restrict__ s1,
                                             const float* __restrict__ s2,
                                             const unsigned* __restrict__ s2mU,
                                             u16* __restrict__ Wp,
                                             float* __restrict__ invZatt)
{
  const int i = blockIdx.x;
  const int b = blockIdx.y;
  const float s1i = s1[b * NI + i];
  const float m = lrelu01(s1i + funkey(s2mU[b]));
  const int j0 = threadIdx.x * 4;
  float4 sv = *(const float4*)(s2 + b * NI + j0);
  float p0 = __expf(lrelu01(s1i + sv.x) - m);
  float p1 = __expf(lrelu01(s1i + sv.y) - m);
  float p2 = __expf(lrelu01(s1i + sv.z) - m);
  float p3 = __expf(lrelu01(s1i + sv.w) - m);
  uint2 pk;
  pk.x = (unsigned)f2bf(p0) | ((unsigned)f2bf(p1) << 16);
  pk.y = (unsigned)f2bf(p2) | ((unsigned)f2bf(p3) << 16);
  *(uint2*)(Wp + (long long)b * NN2 + (long long)i * NI + j0) = pk;
  float lsum = p0 + p1 + p2 + p3;
  __shared__ float red[256];
  red[threadIdx.x] = lsum; __syncthreads();
  for (int st = 128; st > 0; st >>= 1) {
    if (threadIdx.x < st) red[threadIdx.x] += red[threadIdx.x + st];
    __syncthreads();
  }
  if (threadIdx.x == 0) invZatt[b * NI + i] = 1.f / red[0];
}

// cc[b][m] = sum_i W[b][m][i]/Zgl[b][i] + cs2[m]
__global__ __launch_bounds__(256) void cc_kernel(const u16* __restrict__ W,
                                                 const float* __restrict__ Zgl,
                                                 const float* __restrict__ cs2,
                                                 float* __restrict__ cc)
{
  const int m = blockIdx.x, b = blockIdx.y;
  const u16* row = W + (long long)b * NN2 + (long long)m * NI;
  const float* zz = Zgl + (long long)b * NI;
  float s = 0.f;
  for (int i = threadIdx.x; i < NI; i += 256) s += bf2f(row[i]) / zz[i];
  __shared__ float red[256];
  red[threadIdx.x] = s; __syncthreads();
  for (int st = 128; st > 0; st >>= 1) {
    if (threadIdx.x < st) red[threadIdx.x] += red[threadIdx.x + st];
    __syncthreads();
  }
  if (threadIdx.x == 0) cc[(long long)b * NI + m] = red[0] + cs2[m];
}

// ---- LayerNorm phase 1: partial sums, atomics into stats (pre-zeroed) ----
__global__ __launch_bounds__(256) void ln_reduce(const float* __restrict__ T,
                                                 float* __restrict__ stats)
{
  const int b = blockIdx.x, half = blockIdx.y, chunk = blockIdx.z;
  const float* z = T + (long long)b * S2 + (long long)half * S1 + (long long)chunk * 4096;
  float s = 0.f, ss = 0.f;
#pragma unroll
  for (int it = 0; it < 4; it++) {
    float4 v = *(const float4*)(z + it * 1024 + threadIdx.x * 4);
    s += v.x + v.y + v.z + v.w;
    ss = fmaf(v.x, v.x, ss); ss = fmaf(v.y, v.y, ss);
    ss = fmaf(v.z, v.z, ss); ss = fmaf(v.w, v.w, ss);
  }
  for (int off = 1; off < 64; off <<= 1) {
    s += __shfl_xor(s, off);
    ss += __shfl_xor(ss, off);
  }
  __shared__ float r1[4], r2[4];
  const int wid = threadIdx.x >> 6, lane = threadIdx.x & 63;
  if (lane == 0) { r1[wid] = s; r2[wid] = ss; }
  __syncthreads();
  if (threadIdx.x == 0) {
    atomicAdd(&stats[b * 2 + half], r1[0] + r1[1] + r1[2] + r1[3]);
    atomicAdd(&stats[32 + b * 2 + half], r2[0] + r2[1] + r2[2] + r2[3]);
  }
}

// ---- LayerNorm apply + GELU + final gating, 64x64 tiles, LDS transpose of xu ----
__global__ __launch_bounds__(256) void ln_final_t(const float* __restrict__ T,
                                                  const float* __restrict__ stats,
                                                  const float* __restrict__ lnw,
                                                  const float* __restrict__ lnb,
                                                  const float* __restrict__ ct,
                                                  const float* __restrict__ xuT,
                                                  float* __restrict__ outp)
{
  __shared__ float xs[64 * 65];
  const int blk = blockIdx.x;
  const int b = blk >> 4;
  const int n0 = (blk & 15) << 6;
  const int t = threadIdx.x;
  const int tc = t & 63, tr = t >> 6;
  // load xu tile [n][c] coalesced -> LDS [c][nn]
#pragma unroll
  for (int i = 0; i < 16; i++) {
    int nn = i * 4 + tr;
    xs[tc * 65 + nn] = xuT[((long long)b << 16) + (long long)(n0 + nn) * 64 + tc];
  }
  __syncthreads();
  const float inv_n = 1.f / 65536.f;
  const float m0 = stats[b * 2] * inv_n;
  const float m1 = stats[b * 2 + 1] * inv_n;
  const float rs0 = rsqrtf(fmaxf(stats[32 + b * 2] * inv_n - m0 * m0, 0.f) + 1e-5f);
  const float rs1 = rsqrtf(fmaxf(stats[32 + b * 2 + 1] * inv_n - m1 * m1, 0.f) + 1e-5f);
#pragma unroll
  for (int j = 0; j < 16; j++) {
    const int c = j * 4 + tr;
    const int n = n0 + tc;
    const int rem = c * NI + n;
    const long long toff = (long long)b * S2 + rem;
    const float t0 = T[toff];
    const float t1 = T[toff + S1];
    const float w = lnw[rem], bb = lnb[rem];
    const float xn = (t0 - m0) * rs0 * w + bb;
    float ft = (t1 - m1) * rs1 * w + bb;
    ft = 0.5f * ft * (1.f + erff(ft * 0.70710678118654752f));
    const float u = xs[c * 65 + tc];
    const long long oidx = ((long long)b << 16) + rem;
    const float cn = fmaf(ft, ct[oidx] - xn, xn);
    const float el = cn > 0.f ? cn : expm1f(cn);
    outp[oidx] = fmaf(ft, el - u, u);
    outp[BCN + oidx] = cn;
  }
}

extern "C" void kernel_launch(void* const* d_in, const int* in_sizes, int n_in,
                              void* d_out, int out_size, void* d_ws, size_t ws_size,
                              hipStream_t stream)
{
  (void)in_sizes; (void)n_in; (void)out_size; (void)ws_size;
  const float* x      = (const float*)d_in[0];
  const float* ct     = (const float*)d_in[1];
  const float* gdata  = (const float*)d_in[2];
  const float* emb_w  = (const float*)d_in[3];
  const float* emb_b  = (const float*)d_in[4];
  const float* emb2_w = (const float*)d_in[5];
  const float* emb2_b = (const float*)d_in[6];
  const float* att_W  = (const float*)d_in[7];
  const float* att_a  = (const float*)d_in[8];
  // d_in[9] att_GL unused: softmax(relu(GL GL^T)) > 0 everywhere -> mask is a no-op
  const float* uai_w  = (const float*)d_in[10];
  const float* uai_b  = (const float*)d_in[11];
  const float* lin1_w = (const float*)d_in[12];
  const float* lin2_w = (const float*)d_in[13];
  const float* lin2_b = (const float*)d_in[14];
  const float* ln_w   = (const float*)d_in[15];
  const float* ln_b   = (const float*)d_in[16];
  float* outp = (float*)d_out;

  float* ws = (float*)d_ws;
  long long o = 0;
  auto af = [&](long long n) { float* p = ws + o; o += (n + 63) & ~63LL; return p; };
  auto au = [&](long long n) { return (u16*)af((n + 1) / 2); };

  float* h0      = af(S1 * BATCH);
  float* Tacc    = af(S2 * BATCH);
  float* xuaiTf  = af(S1 * BATCH);
  float* s1      = af(BNv);
  float* s2      = af(BNv);
  float* invZatt = af(BNv);
  float* dsum    = af(2 * NI);
  float* cs1v    = af(NI);
  float* cs2v    = af(NI);
  float* v2v     = af(NI);
  float* ccv     = af(BNv);
  float* rb2ext  = af(128);
  float* rl2ext  = af(128);
  // contiguous zero-init region: Zgl, sqv, stats(64), s2mU(16)
  float* zeroreg = af(2 * BNv + 80);
  float* Zgl     = zeroreg;
  float* sqv     = zeroreg + BNv;
  float* stats   = zeroreg + 2 * BNv;
  unsigned* s2mU = (unsigned*)(stats + 64);
  u16* emb2w_bf  = au(NN2);
  u16* h0a_bf    = au(S1 * BATCH);
  u16* hTb       = au(S1 * BATCH);
  u16* xattb     = au(S1 * BATCH);
  u16* xuaiTb    = au(S1 * BATCH);
  u16* g1b       = au(NN2);
  u16* g2tb      = au(NN2);
  u16* G12b      = au(NN2);
  u16* Abig      = au((long long)BATCH * 128 * 2048);
  u16* stack4    = au(256 * 64);
  u16* uaiw_bf   = au(CE * CE);
  u16* bigW      = au(BNN);  // 32 MB: att p matrix, then gram W

  hipMemsetAsync(zeroreg, 0, (2 * BNv + 80) * sizeof(float), stream);

  lap_rowsum<<<2 * NI, 256, 0, stream>>>(gdata, dsum);

  mega_prep<<<11345, 256, 0, stream>>>(
      lin1_w, lin2_w, lin2_b, uai_w, stack4, rb2ext, rl2ext, uaiw_bf,
      emb2_w, emb2w_bf, x, emb_w, emb_b, h0a_bf,
      gdata, dsum, g2tb, g1b, cs1v);

  csv2_kernel<<<NI, 256, 0, stream>>>(gdata + NN2, dsum + NI, cs1v, cs2v, v2v);

  // G12t = (g1@g2)^T = TN(A=g2t, Bt=g1)
  mgemm<64, 64, 6><<<dim3(16, 16, 1), 256, 0, stream>>>(
      g2tb, g1b, nullptr, NI, NI, NI, NI, 0, 0,
      nullptr, G12b, NI, 0, nullptr, nullptr, nullptr, nullptr, nullptr);

  // h0 = h0a @ emb2_w^T + emb2_b
  mgemm<64, 64, 0><<<dim3(16, 16, 1), 256, 0, stream>>>(
      h0a_bf, emb2w_bf, nullptr, NI, NI, NI, NI, 0, 0,
      h0, nullptr, NI, 0, emb2_b, nullptr, nullptr, nullptr, nullptr);

  hT_kernel<<<dim3(64, BATCH), 256, 0, stream>>>(h0, att_W, att_a, hTb, s1, s2, s2mU);
  att_p<<<dim3(NI, BATCH), 256, 0, stream>>>(s1, s2, s2mU, bigW, invZatt);

  // x_att = relu((p@h)/Z) -> bf16 [b][n][c]
  mgemm<64, 64, 1><<<dim3(1, 16, BATCH), 256, 0, stream>>>(
      bigW, hTb, nullptr, NI, NI, NI, NI, NN2, S1,
      nullptr, xattb, CE, S1, invZatt, nullptr, nullptr, nullptr, nullptr);

  // x_uaiT = x_att @ uai_w^T + uai_b (dual fp32+bf16, sq atomics)
  mgemm<64, 64, 2><<<dim3(1, 16, BATCH), 256, 0, stream>>>(
      xattb, uaiw_bf, nullptr, CE, CE, CE, CE, S1, 0,
      xuaiTf, xuaiTb, CE, S1, uai_b, nullptr, nullptr, nullptr, sqv);

  // gram/gl weights (128x128 tiles; exp epilogue; rowsums into Zgl)
  mgemm<128, 128, 3><<<dim3(8, 8, BATCH), 256, 0, stream>>>(
      xuaiTb, xuaiTb, nullptr, CE, CE, CE, CE, S1, S1,
      nullptr, bigW, NI, NN2, sqv, nullptr, nullptr, nullptr, Zgl);

  cc_kernel<<<dim3(NI, BATCH), 256, 0, stream>>>(bigW, Zgl, cs2v, ccv);

  // Abig = [[L1u/Z | L1L1u],[L2u/Z | L2L2u]] bf16
  mgemm<64, 64, 4><<<dim3(16, 4, BATCH), 256, 0, stream>>>(
      stack4, xuaiTb, nullptr, CE, CE, CE, CE, 0, S1,
      nullptr, Abig, 0, (long long)128 * 2048, Zgl, nullptr, nullptr, nullptr, nullptr);

  // Tacc = A1 @ W + rank-1 (XCD z-clustered), then += A2 @ G12t (XCD bx-clustered)
  mgemm<64, 64, 7><<<512, 256, 0, stream>>>(
      Abig, bigW, nullptr, NI, NI, 2048, NI, (long long)128 * 2048, NN2,
      Tacc, nullptr, NI, S2, ccv, v2v, rb2ext, rl2ext, nullptr);
  mgemm<64, 64, 8><<<512, 256, 0, stream>>>(
      Abig + 1024, G12b, nullptr, NI, NI, 2048, NI, (long long)128 * 2048, 0,
      Tacc, nullptr, NI, S2, nullptr, nullptr, nullptr, nullptr, nullptr);

  ln_reduce<<<dim3(BATCH, 2, 16), 256, 0, stream>>>(Tacc, stats);
  ln_final_t<<<256, 256, 0, stream>>>(Tacc, stats, ln_w, ln_b, ct, xuaiTf, outp);
}

// Round 5
// 274.487 us; speedup vs baseline: 1.2235x; 1.2235x over previous
//
#include <hip/hip_runtime.h>
#include <math.h>

typedef unsigned short u16;
typedef __attribute__((ext_vector_type(8))) short short8;
typedef __attribute__((ext_vector_type(4))) float floatx4;

constexpr int BATCH = 16;
constexpr int NI = 1024;
constexpr int CE = 64;
constexpr int CI = 16;
constexpr long long NN2  = (long long)NI * NI;          // 1M
constexpr long long BCN  = (long long)BATCH * CE * NI;  // 1M
constexpr long long BNv  = (long long)BATCH * NI;       // 16K
constexpr long long BNN  = (long long)BATCH * NI * NI;  // 16M
constexpr long long S1 = (long long)CE * NI;            // 65536
constexpr long long S2 = 2 * S1;                        // 131072

__device__ __forceinline__ float lrelu01(float x) { return x > 0.f ? x : 0.01f * x; }

__device__ __forceinline__ u16 f2bf(float f) {
  unsigned u = __builtin_bit_cast(unsigned, f);
  return (u16)((u + 0x7fffu + ((u >> 16) & 1u)) >> 16);  // RNE
}
__device__ __forceinline__ float bf2f(u16 h) {
  unsigned u = ((unsigned)h) << 16;
  return __builtin_bit_cast(float, u);
}
// monotonic uint key for float atomicMax (memset-0 init safe: real-float keys > 0)
__device__ __forceinline__ unsigned fkey(float f) {
  unsigned u = __builtin_bit_cast(unsigned, f);
  return (u & 0x80000000u) ? ~u : (u | 0x80000000u);
}
__device__ __forceinline__ float funkey(unsigned k) {
  unsigned u = (k & 0x80000000u) ? (k & 0x7fffffffu) : ~k;
  return __builtin_bit_cast(float, u);
}

// ================= MFMA TN GEMM: C[r][m] = sum_k A[r][k] * Bt[m][k] ==============
// A, Bt bf16 row-major K-contiguous. BK=64, XOR-swizzled 16B chunks in LDS.
// 4 waves 2x2; wave tile (BM/2)x(BN/2); 16x16x32 MFMAs.
// MODE: 1 rowscale+relu bf16 | 2 dual +colbias + rowsq atomics | 3 gram exp + rowsum |
//       4 Abig scatter w/ Z-div | 5 fused dual-B + rank-1 epilogue fp32 |
//       6 plain bf16 | 9 rowbias bf16
template<int BM, int BN, int MODE>
__global__ __launch_bounds__(256) void mgemm(
    const u16* __restrict__ Ag, const u16* __restrict__ B1g, const u16* __restrict__ B2g,
    int K1, int K, int lda, int ldb, long long bsA, long long bsB1,
    float* __restrict__ Cf, u16* __restrict__ Cb, int ldc, long long bsC,
    const float* __restrict__ aux1, const float* __restrict__ aux2,
    const float* __restrict__ aux3, const float* __restrict__ aux4,
    float* __restrict__ Zout)
{
  constexpr int RM = BM / 2, RN = BN / 2, MI = RM / 16, NJ = RN / 16;
  __shared__ __align__(16) u16 As[BM * 64];
  __shared__ __align__(16) u16 Bs[BN * 64];
  const int z = blockIdx.z;
  const int n0 = blockIdx.x * BN;
  const int r0 = blockIdx.y * BM;
  const u16* Ab = Ag + (long long)z * bsA + (long long)r0 * lda;
  const u16* Bb1 = B1g + (long long)z * bsB1 + (long long)n0 * ldb;
  const int tid = threadIdx.x;
  const int lane = tid & 63;
  const int wid = tid >> 6;
  const int wr = wid >> 1, wc = wid & 1;
  const int q = lane >> 4, mlow = lane & 15;

  floatx4 acc[MI][NJ] = {};

  for (int k0 = 0; k0 < K; k0 += 64) {
    const u16* Asrc = Ab + k0;
    const u16* Bsrc = (k0 < K1) ? (Bb1 + k0)
                                : (B2g + (long long)n0 * ldb + (k0 - K1));
#pragma unroll
    for (int s = 0; s < (BM * 8) / 256; s++) {
      int cid = tid + s * 256;
      int r = cid >> 3, craw = cid & 7;
      uint4 v = *(const uint4*)(Asrc + (long long)r * lda + craw * 8);
      *(uint4*)&As[(r * 8 + (craw ^ (r & 7))) * 8] = v;
    }
#pragma unroll
    for (int s = 0; s < (BN * 8) / 256; s++) {
      int cid = tid + s * 256;
      int r = cid >> 3, craw = cid & 7;
      uint4 v = *(const uint4*)(Bsrc + (long long)r * ldb + craw * 8);
      *(uint4*)&Bs[(r * 8 + (craw ^ (r & 7))) * 8] = v;
    }
    __syncthreads();
#pragma unroll
    for (int kh = 0; kh < 2; kh++) {
      const int kc = kh * 4 + q;
      short8 afr[MI], bfr[NJ];
#pragma unroll
      for (int i = 0; i < MI; i++) {
        int row = wr * RM + i * 16 + mlow;
        afr[i] = *(const short8*)&As[(row * 8 + (kc ^ (row & 7))) * 8];
      }
#pragma unroll
      for (int j = 0; j < NJ; j++) {
        int row = wc * RN + j * 16 + mlow;
        bfr[j] = *(const short8*)&Bs[(row * 8 + (kc ^ (row & 7))) * 8];
      }
#pragma unroll
      for (int i = 0; i < MI; i++)
#pragma unroll
        for (int j = 0; j < NJ; j++)
          acc[i][j] = __builtin_amdgcn_mfma_f32_16x16x32_bf16(afr[i], bfr[j], acc[i][j], 0, 0, 0);
    }
    __syncthreads();
  }

  if constexpr (MODE == 3) {
    const float* sqb = aux1 + (long long)z * NI;
#pragma unroll
    for (int i = 0; i < MI; i++) {
#pragma unroll
      for (int rg = 0; rg < 4; rg++) {
        int r = r0 + wr * RM + i * 16 + q * 4 + rg;
        float sqi = sqb[r];
        float rsum = 0.f;
#pragma unroll
        for (int j = 0; j < NJ; j++) {
          int ncol = n0 + wc * RN + j * 16 + mlow;
          float d2 = fmaxf(sqi + sqb[ncol] - 2.f * acc[i][j][rg], 0.f);
          float w = __expf(__expf(-d2 * (1.f / 128.f)) + (r == ncol ? 1.f : 0.f) - 2.f);
          Cb[(long long)z * bsC + (long long)r * ldc + ncol] = f2bf(w);
          rsum += w;
        }
        rsum += __shfl_xor(rsum, 1);
        rsum += __shfl_xor(rsum, 2);
        rsum += __shfl_xor(rsum, 4);
        rsum += __shfl_xor(rsum, 8);
        if (mlow == 0) atomicAdd(&Zout[(long long)z * NI + r], rsum);
      }
    }
  } else if constexpr (MODE == 2) {
#pragma unroll
    for (int i = 0; i < MI; i++) {
#pragma unroll
      for (int rg = 0; rg < 4; rg++) {
        int r = r0 + wr * RM + i * 16 + q * 4 + rg;
        float sqp = 0.f;
#pragma unroll
        for (int j = 0; j < NJ; j++) {
          int ncol = n0 + wc * RN + j * 16 + mlow;
          float v = acc[i][j][rg] + aux1[ncol];
          long long ix = (long long)z * bsC + (long long)r * ldc + ncol;
          Cf[ix] = v;
          Cb[ix] = f2bf(v);
          sqp = fmaf(v, v, sqp);
        }
        sqp += __shfl_xor(sqp, 1);
        sqp += __shfl_xor(sqp, 2);
        sqp += __shfl_xor(sqp, 4);
        sqp += __shfl_xor(sqp, 8);
        if (mlow == 0) atomicAdd(&Zout[(long long)z * NI + r], sqp);
      }
    }
  } else {
#pragma unroll
    for (int i = 0; i < MI; i++) {
#pragma unroll
      for (int j = 0; j < NJ; j++) {
#pragma unroll
        for (int rg = 0; rg < 4; rg++) {
          int r = r0 + wr * RM + i * 16 + q * 4 + rg;
          int ncol = n0 + wc * RN + j * 16 + mlow;
          float v = acc[i][j][rg];
          if constexpr (MODE == 1) {
            v *= aux1[(long long)z * NI + r];
            v = fmaxf(v, 0.f);
            Cb[(long long)z * bsC + (long long)r * ldc + ncol] = f2bf(v);
          } else if constexpr (MODE == 4) {
            int blk = r >> 6, oo = r & 63;
            int drow = ((blk & 1) << 6) + oo;
            if (blk < 2) v = v / aux1[(long long)z * NI + ncol];  // fold 1/Zgl
            Cb[(long long)z * bsC + (long long)drow * 2048 + (long long)(blk >> 1) * 1024 + ncol] =
                f2bf(v);
          } else if constexpr (MODE == 5) {
            v += aux3[r] * aux1[(long long)z * NI + ncol] + aux4[r] * aux2[ncol];
            Cf[(long long)z * bsC + (long long)r * ldc + ncol] = v;
          } else if constexpr (MODE == 6) {
            Cb[(long long)z * bsC + (long long)r * ldc + ncol] = f2bf(v);
          } else if constexpr (MODE == 9) {
            v += aux3[r];
            Cb[(long long)z * bsC + (long long)r * ldc + ncol] = f2bf(v);
          }
        }
      }
    }
  }
}

// ---------------- lap_rowsum: dr[k][i] = rsqrt(1 + rowsum(graph[k][i])) --------------
__global__ __launch_bounds__(256) void lap_rowsum(const float* __restrict__ gd,
                                                  float* __restrict__ dr)
{
  const int ki = blockIdx.x;
  const float* row = gd + (long long)ki * NI;
  float s = 0.f;
  for (int j = threadIdx.x; j < NI; j += 256) s += row[j];
  __shared__ float red[256];
  red[threadIdx.x] = s; __syncthreads();
  for (int st = 128; st > 0; st >>= 1) {
    if (threadIdx.x < st) red[threadIdx.x] += red[threadIdx.x + st];
    __syncthreads();
  }
  if (threadIdx.x == 0) dr[ki] = rsqrtf(red[0] + 1.f);
}

// ---------------- mega_prep: blockIdx-range dispatch of all prep work ----------------
// [0,97)       small weights: stack4/rb2ext/rl2ext/uaiw_bf/attwT_bf
// [97,4193)    cast emb2_w -> bf16
// [4193,5217)  conv_emb
// [5217,9313)  g_direct (g2^T)
// [9313,10337) g_trans (g1)
// [10337,11361) cs1
__global__ __launch_bounds__(256) void mega_prep(
    const float* __restrict__ l1w, const float* __restrict__ l2w,
    const float* __restrict__ l2b, const float* __restrict__ uaiw,
    const float* __restrict__ attW,
    u16* __restrict__ stack4, float* __restrict__ rb2ext, float* __restrict__ rl2ext,
    u16* __restrict__ uaiw_bf, u16* __restrict__ attwT_bf,
    const float* __restrict__ emb2w, u16* __restrict__ emb2w_bf,
    const float* __restrict__ x, const float* __restrict__ ew,
    const float* __restrict__ eb, u16* __restrict__ h0a,
    const float* __restrict__ gd, const float* __restrict__ dsum,
    u16* __restrict__ g2t, u16* __restrict__ g1,
    float* __restrict__ cs1)
{
  __shared__ float sm[1088];
  const int bid = blockIdx.x;
  const int t = threadIdx.x;
  if (bid < 97) {
    const int gid = bid * 256 + t;
    if (gid < 4096) {
      stack4[gid] = f2bf(l1w[gid]);
    } else if (gid < 8192) {
      stack4[gid] = f2bf(l2w[gid - 4096]);
    } else if (gid < 12288) {
      int tt = gid - 8192, o = tt >> 6, m = tt & 63;
      float s = 0.f;
      for (int c = 0; c < 64; c++) s = fmaf(l1w[o * 64 + c], l1w[c * 64 + m], s);
      stack4[gid] = f2bf(s);
    } else if (gid < 16384) {
      int tt = gid - 12288, o = tt >> 6, m = tt & 63;
      float s = 0.f;
      for (int c = 0; c < 64; c++) s = fmaf(l2w[o * 64 + c], l2w[c * 64 + m], s);
      stack4[gid] = f2bf(s);
    } else if (gid < 16512) {
      int r = gid - 16384;
      rb2ext[r] = (r < 64) ? 0.f : l2b[r - 64];
    } else if (gid < 16640) {
      int r = gid - 16512;
      float v = 0.f;
      if (r >= 64) { int o = r - 64; for (int c = 0; c < 64; c++) v = fmaf(l2w[o * 64 + c], l2b[c], v); }
      rl2ext[r] = v;
    } else if (gid < 20736) {
      uaiw_bf[gid - 16640] = f2bf(uaiw[gid - 16640]);
    } else if (gid < 24832) {
      int idx = gid - 20736;                 // idx = k*64 + e
      int k = idx >> 6, e = idx & 63;
      attwT_bf[idx] = f2bf(attW[e * 64 + k]);
    }
  } else if (bid < 4193) {
    const long long i = (long long)(bid - 97) * 256 + t;
    emb2w_bf[i] = f2bf(emb2w[i]);
  } else if (bid < 5217) {
    const int be = bid - 4193;
    const int b = be >> 6, e = be & 63;
    float* w = sm;
    if (t < CI) w[t] = ew[e * CI + t];
    __syncthreads();
    const float bias = eb[e];
    const float* xb = x + (long long)b * CI * NI;
    u16* outp = h0a + (long long)be * NI;
    for (int n = t; n < NI; n += 256) {
      float a = bias;
#pragma unroll
      for (int c = 0; c < CI; c++) a = fmaf(xb[c * NI + n], w[c], a);
      outp[n] = f2bf(lrelu01(a));
    }
  } else if (bid < 9313) {
    const long long idx = (long long)(bid - 5217) * 256 + t;
    const int m = (int)(idx >> 10), j = (int)(idx & 1023);
    const float* d = dsum + NI;
    float v = (gd[NN2 + idx] + (m == j ? 1.f : 0.f)) * d[m] * d[j];
    g2t[idx] = f2bf(v);
  } else if (bid < 10337) {
    const int sub = bid - 9313;
    const int bx = (sub & 31) * 32, by = (sub >> 5) * 32;
    const int lx = t & 31, ly = t >> 5;  // 32x8
    float* tile = sm;                    // 32x33
    for (int yy = ly; yy < 32; yy += 8)
      tile[yy * 33 + lx] = gd[(long long)(by + yy) * NI + bx + lx];
    __syncthreads();
    for (int yy = ly; yy < 32; yy += 8) {
      const int i = bx + yy, j = by + lx;
      float v = (tile[lx * 33 + yy] + (i == j ? 1.f : 0.f)) * dsum[i] * dsum[j];
      g1[(long long)i * NI + j] = f2bf(v);
    }
  } else {
    const int n = bid - 10337;
    float s = 0.f;
    for (int i = t; i < NI; i += 256) s = fmaf(gd[(long long)n * NI + i], dsum[i], s);
    float* red = sm;
    red[t] = s; __syncthreads();
    for (int st = 128; st > 0; st >>= 1) {
      if (t < st) red[t] += red[t + st];
      __syncthreads();
    }
    if (t == 0) cs1[n] = dsum[n] * (red[0] + dsum[n]);
  }
}

// cs2[m] = colsum g2; v2[m] = (cs1 @ g2)[m]
__global__ __launch_bounds__(256) void csv2_kernel(const float* __restrict__ gd1,
                                                   const float* __restrict__ d,
                                                   const float* __restrict__ cs1,
                                                   float* __restrict__ cs2,
                                                   float* __restrict__ v2)
{
  const int m = blockIdx.x;
  float s = 0.f, sv = 0.f;
  for (int n = threadIdx.x; n < NI; n += 256) {
    float g = gd1[(long long)m * NI + n] * d[n];
    s += g;
    sv = fmaf(g, cs1[n], sv);
  }
  __shared__ float r1[256], r2[256];
  r1[threadIdx.x] = s; r2[threadIdx.x] = sv; __syncthreads();
  for (int st = 128; st > 0; st >>= 1) {
    if (threadIdx.x < st) { r1[threadIdx.x] += r1[threadIdx.x + st]; r2[threadIdx.x] += r2[threadIdx.x + st]; }
    __syncthreads();
  }
  if (threadIdx.x == 0) {
    cs2[m] = d[m] * (r1[0] + d[m]);
    v2[m] = d[m] * (r2[0] + d[m] * cs1[m]);
  }
}

// s1/s2 scores from hT[b][c][n] (coalesced over n) + per-batch s2 max
__global__ __launch_bounds__(256) void s12_kernel(const u16* __restrict__ hTb,
                                                  const float* __restrict__ atta,
                                                  float* __restrict__ s1,
                                                  float* __restrict__ s2,
                                                  unsigned* __restrict__ s2mU)
{
  const int b = blockIdx.y;
  const int n = blockIdx.x * 256 + threadIdx.x;
  const u16* base = hTb + (long long)b * S1 + n;
  float v1 = 0.f, v2 = 0.f;
#pragma unroll 8
  for (int c = 0; c < 64; c++) {
    float h = bf2f(base[(long long)c * NI]);
    v1 = fmaf(h, atta[c], v1);
    v2 = fmaf(h, atta[64 + c], v2);
  }
  s1[(long long)b * NI + n] = v1;
  s2[(long long)b * NI + n] = v2;
  float mx = v2;
  for (int off = 1; off < 64; off <<= 1) mx = fmaxf(mx, __shfl_xor(mx, off));
  if ((threadIdx.x & 63) == 0) atomicMax(&s2mU[b], fkey(mx));
}

// p (bf16) = exp(lrelu(s1_i+s2_j) - rowmax); invZatt = 1/rowsum. One wave per row.
__global__ __launch_bounds__(256) void att_p(const float* __restrict__ s1,
                                             const float* __restrict__ s2,
                                             const unsigned* __restrict__ s2mU,
                                             u16* __restrict__ Wp,
                                             float* __restrict__ invZatt)
{
  const int b = blockIdx.y;
  const int wid = threadIdx.x >> 6, lane = threadIdx.x & 63;
  const int i = blockIdx.x * 4 + wid;
  const float s1i = s1[(long long)b * NI + i];
  const float m = lrelu01(s1i + funkey(s2mU[b]));
  const float* s2b = s2 + (long long)b * NI;
  u16* row = Wp + (long long)b * NN2 + (long long)i * NI;
  float lsum = 0.f;
#pragma unroll
  for (int it = 0; it < 4; it++) {
    const int j0 = it * 256 + lane * 4;
    float4 sv = *(const float4*)(s2b + j0);
    float p0 = __expf(lrelu01(s1i + sv.x) - m);
    float p1 = __expf(lrelu01(s1i + sv.y) - m);
    float p2 = __expf(lrelu01(s1i + sv.z) - m);
    float p3 = __expf(lrelu01(s1i + sv.w) - m);
    uint2 pk;
    pk.x = (unsigned)f2bf(p0) | ((unsigned)f2bf(p1) << 16);
    pk.y = (unsigned)f2bf(p2) | ((unsigned)f2bf(p3) << 16);
    *(uint2*)(row + j0) = pk;
    lsum += p0 + p1 + p2 + p3;
  }
  for (int off = 1; off < 64; off <<= 1) lsum += __shfl_xor(lsum, off);
  if (lane == 0) invZatt[(long long)b * NI + i] = 1.f / lsum;
}

// cc[b][m] = sum_i W[b][m][i]/Zgl[b][i] + cs2[m]. One wave per row.
__global__ __launch_bounds__(256) void cc_kernel(const u16* __restrict__ W,
                                                 const float* __restrict__ Zgl,
                                                 const float* __restrict__ cs2,
                                                 float* __restrict__ cc)
{
  const int b = blockIdx.y;
  const int wid = threadIdx.x >> 6, lane = threadIdx.x & 63;
  const int m = blockIdx.x * 4 + wid;
  const u16* row = W + (long long)b * NN2 + (long long)m * NI;
  const float* zz = Zgl + (long long)b * NI;
  float s = 0.f;
#pragma unroll
  for (int it = 0; it < 4; it++) {
    const int j0 = it * 256 + lane * 4;
    uint2 pk = *(const uint2*)(row + j0);
    float4 zv = *(const float4*)(zz + j0);
    s += bf2f((u16)(pk.x & 0xffff)) / zv.x + bf2f((u16)(pk.x >> 16)) / zv.y
       + bf2f((u16)(pk.y & 0xffff)) / zv.z + bf2f((u16)(pk.y >> 16)) / zv.w;
  }
  for (int off = 1; off < 64; off <<= 1) s += __shfl_xor(s, off);
  if (lane == 0) cc[(long long)b * NI + m] = s + cs2[m];
}

// ---- LayerNorm phase 1: partial sums, atomics into stats (pre-zeroed) ----
__global__ __launch_bounds__(256) void ln_reduce(const float* __restrict__ T,
                                                 float* __restrict__ stats)
{
  const int b = blockIdx.x, half = blockIdx.y, chunk = blockIdx.z;
  const float* z = T + (long long)b * S2 + (long long)half * S1 + (long long)chunk * 4096;
  float s = 0.f, ss = 0.f;
#pragma unroll
  for (int it = 0; it < 4; it++) {
    float4 v = *(const float4*)(z + it * 1024 + threadIdx.x * 4);
    s += v.x + v.y + v.z + v.w;
    ss = fmaf(v.x, v.x, ss); ss = fmaf(v.y, v.y, ss);
    ss = fmaf(v.z, v.z, ss); ss = fmaf(v.w, v.w, ss);
  }
  for (int off = 1; off < 64; off <<= 1) {
    s += __shfl_xor(s, off);
    ss += __shfl_xor(ss, off);
  }
  __shared__ float r1[4], r2[4];
  const int wid = threadIdx.x >> 6, lane = threadIdx.x & 63;
  if (lane == 0) { r1[wid] = s; r2[wid] = ss; }
  __syncthreads();
  if (threadIdx.x == 0) {
    atomicAdd(&stats[b * 2 + half], r1[0] + r1[1] + r1[2] + r1[3]);
    atomicAdd(&stats[32 + b * 2 + half], r2[0] + r2[1] + r2[2] + r2[3]);
  }
}

// ---- LayerNorm apply + GELU + final gating, 64x64 tiles, LDS transpose of xu ----
__global__ __launch_bounds__(256) void ln_final_t(const float* __restrict__ T,
                                                  const float* __restrict__ stats,
                                                  const float* __restrict__ lnw,
                                                  const float* __restrict__ lnb,
                                                  const float* __restrict__ ct,
                                                  const float* __restrict__ xuT,
                                                  float* __restrict__ outp)
{
  __shared__ float xs[64 * 65];
  const int blk = blockIdx.x;
  const int b = blk >> 4;
  const int n0 = (blk & 15) << 6;
  const int t = threadIdx.x;
  const int tc = t & 63, tr = t >> 6;
#pragma unroll
  for (int i = 0; i < 16; i++) {
    int nn = i * 4 + tr;
    xs[tc * 65 + nn] = xuT[((long long)b << 16) + (long long)(n0 + nn) * 64 + tc];
  }
  __syncthreads();
  const float inv_n = 1.f / 65536.f;
  const float m0 = stats[b * 2] * inv_n;
  const float m1 = stats[b * 2 + 1] * inv_n;
  const float rs0 = rsqrtf(fmaxf(stats[32 + b * 2] * inv_n - m0 * m0, 0.f) + 1e-5f);
  const float rs1 = rsqrtf(fmaxf(stats[32 + b * 2 + 1] * inv_n - m1 * m1, 0.f) + 1e-5f);
#pragma unroll
  for (int j = 0; j < 16; j++) {
    const int c = j * 4 + tr;
    const int n = n0 + tc;
    const int rem = c * NI + n;
    const long long toff = (long long)b * S2 + rem;
    const float t0 = T[toff];
    const float t1 = T[toff + S1];
    const float w = lnw[rem], bb = lnb[rem];
    const float xn = (t0 - m0) * rs0 * w + bb;
    float ft = (t1 - m1) * rs1 * w + bb;
    ft = 0.5f * ft * (1.f + erff(ft * 0.70710678118654752f));
    const float u = xs[c * 65 + tc];
    const long long oidx = ((long long)b << 16) + rem;
    const float cn = fmaf(ft, ct[oidx] - xn, xn);
    const float el = cn > 0.f ? cn : expm1f(cn);
    outp[oidx] = fmaf(ft, el - u, u);
    outp[BCN + oidx] = cn;
  }
}

extern "C" void kernel_launch(void* const* d_in, const int* in_sizes, int n_in,
                              void* d_out, int out_size, void* d_ws, size_t ws_size,
                              hipStream_t stream)
{
  (void)in_sizes; (void)n_in; (void)out_size; (void)ws_size;
  const float* x      = (const float*)d_in[0];
  const float* ct     = (const float*)d_in[1];
  const float* gdata  = (const float*)d_in[2];
  const float* emb_w  = (const float*)d_in[3];
  const float* emb_b  = (const float*)d_in[4];
  const float* emb2_w = (const float*)d_in[5];
  const float* emb2_b = (const float*)d_in[6];
  const float* att_W  = (const float*)d_in[7];
  const float* att_a  = (const float*)d_in[8];
  // d_in[9] att_GL unused: softmax(relu(GL GL^T)) > 0 everywhere -> mask is a no-op
  const float* uai_w  = (const float*)d_in[10];
  const float* uai_b  = (const float*)d_in[11];
  const float* lin1_w = (const float*)d_in[12];
  const float* lin2_w = (const float*)d_in[13];
  const float* lin2_b = (const float*)d_in[14];
  const float* ln_w   = (const float*)d_in[15];
  const float* ln_b   = (const float*)d_in[16];
  float* outp = (float*)d_out;

  float* ws = (float*)d_ws;
  long long o = 0;
  auto af = [&](long long n) { float* p = ws + o; o += (n + 63) & ~63LL; return p; };
  auto au = [&](long long n) { return (u16*)af((n + 1) / 2); };

  float* Tacc    = af(S2 * BATCH);
  float* xuaiTf  = af(S1 * BATCH);
  float* s1      = af(BNv);
  float* s2      = af(BNv);
  float* invZatt = af(BNv);
  float* dsum    = af(2 * NI);
  float* cs1v    = af(NI);
  float* cs2v    = af(NI);
  float* v2v     = af(NI);
  float* ccv     = af(BNv);
  float* rb2ext  = af(128);
  float* rl2ext  = af(128);
  // contiguous zero-init region: Zgl, sqv, stats(64), s2mU(16)
  float* zeroreg = af(2 * BNv + 80);
  float* Zgl     = zeroreg;
  float* sqv     = zeroreg + BNv;
  float* stats   = zeroreg + 2 * BNv;
  unsigned* s2mU = (unsigned*)(stats + 64);
  u16* emb2w_bf  = au(NN2);
  u16* h0a_bf    = au(S1 * BATCH);
  u16* h0Tb      = au(S1 * BATCH);   // [b][n][e]
  u16* hTb       = au(S1 * BATCH);   // [b][c][n]
  u16* xattb     = au(S1 * BATCH);   // [b][n][c]
  u16* xuaiTb    = au(S1 * BATCH);   // [b][n][c]
  u16* g1b       = au(NN2);
  u16* g2tb      = au(NN2);
  u16* G12b      = au(NN2);
  u16* Abig      = au((long long)BATCH * 128 * 2048);
  u16* stack4    = au(256 * 64);
  u16* uaiw_bf   = au(CE * CE);
  u16* attwT_bf  = au(CE * CE);
  u16* bigW      = au(BNN);  // 32 MB: att p matrix, then gram W

  hipMemsetAsync(zeroreg, 0, (2 * BNv + 80) * sizeof(float), stream);

  lap_rowsum<<<2 * NI, 256, 0, stream>>>(gdata, dsum);

  mega_prep<<<11361, 256, 0, stream>>>(
      lin1_w, lin2_w, lin2_b, uai_w, att_W,
      stack4, rb2ext, rl2ext, uaiw_bf, attwT_bf,
      emb2_w, emb2w_bf, x, emb_w, emb_b, h0a_bf,
      gdata, dsum, g2tb, g1b, cs1v);

  csv2_kernel<<<NI, 256, 0, stream>>>(gdata + NN2, dsum + NI, cs1v, cs2v, v2v);

  // G12t = (g1@g2)^T = TN(A=g2t, Bt=g1)
  mgemm<64, 64, 6><<<dim3(16, 16, 1), 256, 0, stream>>>(
      g2tb, g1b, nullptr, NI, NI, NI, NI, 0, 0,
      nullptr, G12b, NI, 0, nullptr, nullptr, nullptr, nullptr, nullptr);

  // h0T[b][m][e] = (emb2w @ h0a_b^T)[m][e] + emb2_b[m]  (rowbias, bf16)
  mgemm<64, 64, 9><<<dim3(1, 16, BATCH), 256, 0, stream>>>(
      emb2w_bf, h0a_bf, nullptr, NI, NI, NI, NI, 0, S1,
      nullptr, h0Tb, CE, S1, nullptr, nullptr, emb2_b, nullptr, nullptr);

  // hT[b][c][n] = (attW^T @ h0T_b^T)  (K=64, bf16)
  mgemm<64, 64, 6><<<dim3(16, 1, BATCH), 256, 0, stream>>>(
      attwT_bf, h0Tb, nullptr, CE, CE, CE, CE, 0, S1,
      nullptr, hTb, NI, S1, nullptr, nullptr, nullptr, nullptr, nullptr);

  s12_kernel<<<dim3(4, BATCH), 256, 0, stream>>>(hTb, att_a, s1, s2, s2mU);
  att_p<<<dim3(NI / 4, BATCH), 256, 0, stream>>>(s1, s2, s2mU, bigW, invZatt);

  // x_att = relu((p@h)/Z) -> bf16 [b][n][c]
  mgemm<64, 64, 1><<<dim3(1, 16, BATCH), 256, 0, stream>>>(
      bigW, hTb, nullptr, NI, NI, NI, NI, NN2, S1,
      nullptr, xattb, CE, S1, invZatt, nullptr, nullptr, nullptr, nullptr);

  // x_uaiT = x_att @ uai_w^T + uai_b (dual fp32+bf16, rowsq atomics into sqv)
  mgemm<64, 64, 2><<<dim3(1, 16, BATCH), 256, 0, stream>>>(
      xattb, uaiw_bf, nullptr, CE, CE, CE, CE, S1, 0,
      xuaiTf, xuaiTb, CE, S1, uai_b, nullptr, nullptr, nullptr, sqv);

  // gram/gl weights (128x128 tiles; exp epilogue; rowsums into Zgl)
  mgemm<128, 128, 3><<<dim3(8, 8, BATCH), 256, 0, stream>>>(
      xuaiTb, xuaiTb, nullptr, CE, CE, CE, CE, S1, S1,
      nullptr, bigW, NI, NN2, sqv, nullptr, nullptr, nullptr, Zgl);

  cc_kernel<<<dim3(NI / 4, BATCH), 256, 0, stream>>>(bigW, Zgl, cs2v, ccv);

  // Abig = [[L1u/Z | L1L1u],[L2u/Z | L2L2u]] bf16
  mgemm<64, 64, 4><<<dim3(16, 4, BATCH), 256, 0, stream>>>(
      stack4, xuaiTb, nullptr, CE, CE, CE, CE, 0, S1,
      nullptr, Abig, 0, (long long)128 * 2048, Zgl, nullptr, nullptr, nullptr, nullptr);

  // fused: Tacc = Abig @ [W ; G12t] + b2 (x) cc + (L2 b2) (x) v2   (single dispatch)
  mgemm<64, 128, 5><<<dim3(8, 2, BATCH), 256, 0, stream>>>(
      Abig, bigW, G12b, NI, 2 * NI, 2048, NI, (long long)128 * 2048, NN2,
      Tacc, nullptr, NI, S2, ccv, v2v, rb2ext, rl2ext, nullptr);

  ln_reduce<<<dim3(BATCH, 2, 16), 256, 0, stream>>>(Tacc, stats);
  ln_final_t<<<256, 256, 0, stream>>>(Tacc, stats, ln_w, ln_b, ct, xuaiTf, outp);
}

// Round 6
// 269.759 us; speedup vs baseline: 1.2449x; 1.0175x over previous
//
#include <hip/hip_runtime.h>
#include <math.h>

typedef unsigned short u16;
typedef __attribute__((ext_vector_type(8))) short short8;
typedef __attribute__((ext_vector_type(4))) float floatx4;

constexpr int BATCH = 16;
constexpr int NI = 1024;
constexpr int CE = 64;
constexpr int CI = 16;
constexpr long long NN2  = (long long)NI * NI;          // 1M
constexpr long long BCN  = (long long)BATCH * CE * NI;  // 1M
constexpr long long BNv  = (long long)BATCH * NI;       // 16K
constexpr long long BNN  = (long long)BATCH * NI * NI;  // 16M
constexpr long long S1 = (long long)CE * NI;            // 65536
constexpr long long S2 = 2 * S1;                        // 131072

__device__ __forceinline__ float lrelu01(float x) { return x > 0.f ? x : 0.01f * x; }

__device__ __forceinline__ u16 f2bf(float f) {
  unsigned u = __builtin_bit_cast(unsigned, f);
  return (u16)((u + 0x7fffu + ((u >> 16) & 1u)) >> 16);  // RNE
}
__device__ __forceinline__ float bf2f(u16 h) {
  unsigned u = ((unsigned)h) << 16;
  return __builtin_bit_cast(float, u);
}
// monotonic uint key for float atomicMax (memset-0 init safe: real-float keys > 0)
__device__ __forceinline__ unsigned fkey(float f) {
  unsigned u = __builtin_bit_cast(unsigned, f);
  return (u & 0x80000000u) ? ~u : (u | 0x80000000u);
}
__device__ __forceinline__ float funkey(unsigned k) {
  unsigned u = (k & 0x80000000u) ? (k & 0x7fffffffu) : ~k;
  return __builtin_bit_cast(float, u);
}

// ================= MFMA TN GEMM: C[r][m] = sum_k A[r][k] * Bt[m][k] ==============
// A, Bt bf16 row-major K-contiguous. BK=64, XOR-swizzled 16B chunks in LDS.
// 4 waves 2x2; wave tile (BM/2)x(BN/2); 16x16x32 MFMAs.
// MODE: 2 bf16 +colbias + rowsq atomics | 3 gram exp + rowsum | 4 Abig scatter w/ Z-div |
//       5 fused dual-B + rank-1 epilogue + LN-stats atomics | 6 plain bf16 |
//       10 A computed on the fly (attention p) + rowscale+relu bf16 |
//       11 rowbias bf16 + fused s1/s2/s2max epilogue
template<int BM, int BN, int MODE>
__global__ __launch_bounds__(256) void mgemm(
    const u16* __restrict__ Ag, const u16* __restrict__ B1g, const u16* __restrict__ B2g,
    int K1, int K, int lda, int ldb, long long bsA, long long bsB1,
    float* __restrict__ Cf, u16* __restrict__ Cb, int ldc, long long bsC,
    const float* __restrict__ aux1, const float* __restrict__ aux2,
    const float* __restrict__ aux3, const float* __restrict__ aux4,
    float* __restrict__ Zout)
{
  constexpr int RM = BM / 2, RN = BN / 2, MI = RM / 16, NJ = RN / 16;
  __shared__ __align__(16) u16 As[BM * 64];
  __shared__ __align__(16) u16 Bs[BN * 64];
  const int z = blockIdx.z;
  const int n0 = blockIdx.x * BN;
  const int r0 = blockIdx.y * BM;
  const u16* Ab = Ag + (long long)z * bsA + (long long)r0 * lda;
  const u16* Bb1 = B1g + (long long)z * bsB1 + (long long)n0 * ldb;
  const int tid = threadIdx.x;
  const int lane = tid & 63;
  const int wid = tid >> 6;
  const int wr = wid >> 1, wc = wid & 1;
  const int q = lane >> 4, mlow = lane & 15;

  floatx4 acc[MI][NJ] = {};

  for (int k0 = 0; k0 < K; k0 += 64) {
    if constexpr (MODE == 10) {
      // A-tile = attention p computed on the fly from s1 (aux2), s2 (aux3), s2max (Zout)
      const float* s1z = aux2 + (long long)z * NI;
      const float* s2z = aux3 + (long long)z * NI;
      const float mb = funkey(((const unsigned*)Zout)[z]);
#pragma unroll
      for (int s = 0; s < (BM * 8) / 256; s++) {
        int cid = tid + s * 256;
        int r = cid >> 3, craw = cid & 7;
        float s1r = s1z[r0 + r];
        float mr = lrelu01(s1r + mb);
        const float* sp = s2z + k0 + craw * 8;
        float4 sa = *(const float4*)sp;
        float4 sb = *(const float4*)(sp + 4);
        float p0 = __expf(lrelu01(s1r + sa.x) - mr);
        float p1 = __expf(lrelu01(s1r + sa.y) - mr);
        float p2 = __expf(lrelu01(s1r + sa.z) - mr);
        float p3 = __expf(lrelu01(s1r + sa.w) - mr);
        float p4 = __expf(lrelu01(s1r + sb.x) - mr);
        float p5 = __expf(lrelu01(s1r + sb.y) - mr);
        float p6 = __expf(lrelu01(s1r + sb.z) - mr);
        float p7 = __expf(lrelu01(s1r + sb.w) - mr);
        uint4 v;
        v.x = (unsigned)f2bf(p0) | ((unsigned)f2bf(p1) << 16);
        v.y = (unsigned)f2bf(p2) | ((unsigned)f2bf(p3) << 16);
        v.z = (unsigned)f2bf(p4) | ((unsigned)f2bf(p5) << 16);
        v.w = (unsigned)f2bf(p6) | ((unsigned)f2bf(p7) << 16);
        *(uint4*)&As[(r * 8 + (craw ^ (r & 7))) * 8] = v;
      }
    } else {
      const u16* Asrc = Ab + k0;
#pragma unroll
      for (int s = 0; s < (BM * 8) / 256; s++) {
        int cid = tid + s * 256;
        int r = cid >> 3, craw = cid & 7;
        uint4 v = *(const uint4*)(Asrc + (long long)r * lda + craw * 8);
        *(uint4*)&As[(r * 8 + (craw ^ (r & 7))) * 8] = v;
      }
    }
    {
      const u16* Bsrc = (k0 < K1) ? (Bb1 + k0)
                                  : (B2g + (long long)n0 * ldb + (k0 - K1));
#pragma unroll
      for (int s = 0; s < (BN * 8) / 256; s++) {
        int cid = tid + s * 256;
        int r = cid >> 3, craw = cid & 7;
        uint4 v = *(const uint4*)(Bsrc + (long long)r * ldb + craw * 8);
        *(uint4*)&Bs[(r * 8 + (craw ^ (r & 7))) * 8] = v;
      }
    }
    __syncthreads();
#pragma unroll
    for (int kh = 0; kh < 2; kh++) {
      const int kc = kh * 4 + q;
      short8 afr[MI], bfr[NJ];
#pragma unroll
      for (int i = 0; i < MI; i++) {
        int row = wr * RM + i * 16 + mlow;
        afr[i] = *(const short8*)&As[(row * 8 + (kc ^ (row & 7))) * 8];
      }
#pragma unroll
      for (int j = 0; j < NJ; j++) {
        int row = wc * RN + j * 16 + mlow;
        bfr[j] = *(const short8*)&Bs[(row * 8 + (kc ^ (row & 7))) * 8];
      }
#pragma unroll
      for (int i = 0; i < MI; i++)
#pragma unroll
        for (int j = 0; j < NJ; j++)
          acc[i][j] = __builtin_amdgcn_mfma_f32_16x16x32_bf16(afr[i], bfr[j], acc[i][j], 0, 0, 0);
    }
    __syncthreads();
  }

  if constexpr (MODE == 3) {
    const float* sqb = aux1 + (long long)z * NI;
#pragma unroll
    for (int i = 0; i < MI; i++) {
#pragma unroll
      for (int rg = 0; rg < 4; rg++) {
        int r = r0 + wr * RM + i * 16 + q * 4 + rg;
        float sqi = sqb[r];
        float rsum = 0.f;
#pragma unroll
        for (int j = 0; j < NJ; j++) {
          int ncol = n0 + wc * RN + j * 16 + mlow;
          float d2 = fmaxf(sqi + sqb[ncol] - 2.f * acc[i][j][rg], 0.f);
          float w = __expf(__expf(-d2 * (1.f / 128.f)) + (r == ncol ? 1.f : 0.f) - 2.f);
          Cb[(long long)z * bsC + (long long)r * ldc + ncol] = f2bf(w);
          rsum += w;
        }
        rsum += __shfl_xor(rsum, 1);
        rsum += __shfl_xor(rsum, 2);
        rsum += __shfl_xor(rsum, 4);
        rsum += __shfl_xor(rsum, 8);
        if (mlow == 0) atomicAdd(&Zout[(long long)z * NI + r], rsum);
      }
    }
  } else if constexpr (MODE == 2) {
#pragma unroll
    for (int i = 0; i < MI; i++) {
#pragma unroll
      for (int rg = 0; rg < 4; rg++) {
        int r = r0 + wr * RM + i * 16 + q * 4 + rg;
        float sqp = 0.f;
#pragma unroll
        for (int j = 0; j < NJ; j++) {
          int ncol = n0 + wc * RN + j * 16 + mlow;
          float v = acc[i][j][rg] + aux1[ncol];
          Cb[(long long)z * bsC + (long long)r * ldc + ncol] = f2bf(v);
          sqp = fmaf(v, v, sqp);
        }
        sqp += __shfl_xor(sqp, 1);
        sqp += __shfl_xor(sqp, 2);
        sqp += __shfl_xor(sqp, 4);
        sqp += __shfl_xor(sqp, 8);
        if (mlow == 0) atomicAdd(&Zout[(long long)z * NI + r], sqp);
      }
    }
  } else if constexpr (MODE == 11) {
    // rowbias bf16 write + s1/s2 row-dots with w1 (aux1), w2 (aux2); bias aux3;
    // s1 -> Cf, s2 -> Zout, per-batch max -> atomicMax((unsigned*)B2g)[z]
    float* sred = (float*)As;  // [64][2] s1-halves, +128: s2-halves
#pragma unroll
    for (int i = 0; i < MI; i++) {
#pragma unroll
      for (int rg = 0; rg < 4; rg++) {
        int rloc = wr * RM + i * 16 + q * 4 + rg;
        int r = r0 + rloc;
        float rb = aux3[r];
        float ps1 = 0.f, ps2 = 0.f;
#pragma unroll
        for (int j = 0; j < NJ; j++) {
          int ncol = n0 + wc * RN + j * 16 + mlow;
          float v = acc[i][j][rg] + rb;
          Cb[(long long)z * bsC + (long long)r * ldc + ncol] = f2bf(v);
          ps1 = fmaf(v, aux1[ncol], ps1);
          ps2 = fmaf(v, aux2[ncol], ps2);
        }
        ps1 += __shfl_xor(ps1, 1); ps1 += __shfl_xor(ps1, 2);
        ps1 += __shfl_xor(ps1, 4); ps1 += __shfl_xor(ps1, 8);
        ps2 += __shfl_xor(ps2, 1); ps2 += __shfl_xor(ps2, 2);
        ps2 += __shfl_xor(ps2, 4); ps2 += __shfl_xor(ps2, 8);
        if (mlow == 0) { sred[rloc * 2 + wc] = ps1; sred[128 + rloc * 2 + wc] = ps2; }
      }
    }
    __syncthreads();
    if (tid < 64) {
      float v1 = sred[tid * 2] + sred[tid * 2 + 1];
      float v2 = sred[128 + tid * 2] + sred[128 + tid * 2 + 1];
      Cf[(long long)z * NI + r0 + tid] = v1;
      Zout[(long long)z * NI + r0 + tid] = v2;
      float mx = v2;
      for (int off = 1; off < 64; off <<= 1) mx = fmaxf(mx, __shfl_xor(mx, off));
      if (tid == 0) atomicMax((unsigned*)B2g + z, fkey(mx));
    }
  } else {
    float ts = 0.f, tss = 0.f;  // MODE5 LN-stats accumulators
#pragma unroll
    for (int i = 0; i < MI; i++) {
#pragma unroll
      for (int j = 0; j < NJ; j++) {
#pragma unroll
        for (int rg = 0; rg < 4; rg++) {
          int r = r0 + wr * RM + i * 16 + q * 4 + rg;
          int ncol = n0 + wc * RN + j * 16 + mlow;
          float v = acc[i][j][rg];
          if constexpr (MODE == 10) {
            v *= aux1[(long long)z * NI + r];
            v = fmaxf(v, 0.f);
            Cb[(long long)z * bsC + (long long)r * ldc + ncol] = f2bf(v);
          } else if constexpr (MODE == 4) {
            int blk = r >> 6, oo = r & 63;
            int drow = ((blk & 1) << 6) + oo;
            if (blk < 2) v = v / aux1[(long long)z * NI + ncol];  // fold 1/Zgl
            Cb[(long long)z * bsC + (long long)drow * 2048 + (long long)(blk >> 1) * 1024 + ncol] =
                f2bf(v);
          } else if constexpr (MODE == 5) {
            v += aux3[r] * aux1[(long long)z * NI + ncol] + aux4[r] * aux2[ncol];
            Cf[(long long)z * bsC + (long long)r * ldc + ncol] = v;
            ts += v;
            tss = fmaf(v, v, tss);
          } else if constexpr (MODE == 6) {
            Cb[(long long)z * bsC + (long long)r * ldc + ncol] = f2bf(v);
          }
        }
      }
    }
    if constexpr (MODE == 5) {
      // block-level LN partial stats -> atomics; half = r-tile (rows 0-63 xn, 64-127 ft)
      float* red = (float*)As;  // 512 floats
      red[tid] = ts; red[256 + tid] = tss;
      __syncthreads();
      for (int st = 128; st > 0; st >>= 1) {
        if (tid < st) { red[tid] += red[tid + st]; red[256 + tid] += red[256 + tid + st]; }
        __syncthreads();
      }
      if (tid == 0) {
        const int half = r0 >> 6;
        atomicAdd(&Zout[z * 2 + half], red[0]);
        atomicAdd(&Zout[32 + z * 2 + half], red[256]);
      }
    }
  }
}

// ---------------- lap_rowsum: dr[k][i] = rsqrt(1 + rowsum(graph[k][i])) --------------
__global__ __launch_bounds__(256) void lap_rowsum(const float* __restrict__ gd,
                                                  float* __restrict__ dr)
{
  const int ki = blockIdx.x;
  const float* row = gd + (long long)ki * NI;
  float s = 0.f;
  for (int j = threadIdx.x; j < NI; j += 256) s += row[j];
  __shared__ float red[256];
  red[threadIdx.x] = s; __syncthreads();
  for (int st = 128; st > 0; st >>= 1) {
    if (threadIdx.x < st) red[threadIdx.x] += red[threadIdx.x + st];
    __syncthreads();
  }
  if (threadIdx.x == 0) dr[ki] = rsqrtf(red[0] + 1.f);
}

// ---------------- mega_prep: blockIdx-range dispatch of all prep work ----------------
// [0,98)        small weights: stack4/rb2ext/rl2ext/uaiw_bf/attwT_bf/w12
// [98,4194)     cast emb2_w -> bf16
// [4194,5218)   conv_emb
// [5218,9314)   g_direct (g2^T)
// [9314,10338)  g_trans (g1)
// [10338,11362) cs1
__global__ __launch_bounds__(256) void mega_prep(
    const float* __restrict__ l1w, const float* __restrict__ l2w,
    const float* __restrict__ l2b, const float* __restrict__ uaiw,
    const float* __restrict__ attW, const float* __restrict__ atta,
    u16* __restrict__ stack4, float* __restrict__ rb2ext, float* __restrict__ rl2ext,
    u16* __restrict__ uaiw_bf, u16* __restrict__ attwT_bf, float* __restrict__ w12,
    const float* __restrict__ emb2w, u16* __restrict__ emb2w_bf,
    const float* __restrict__ x, const float* __restrict__ ew,
    const float* __restrict__ eb, u16* __restrict__ h0a,
    const float* __restrict__ gd, const float* __restrict__ dsum,
    u16* __restrict__ g2t, u16* __restrict__ g1,
    float* __restrict__ cs1)
{
  __shared__ float sm[1088];
  const int bid = blockIdx.x;
  const int t = threadIdx.x;
  if (bid < 98) {
    const int gid = bid * 256 + t;
    if (gid < 4096) {
      stack4[gid] = f2bf(l1w[gid]);
    } else if (gid < 8192) {
      stack4[gid] = f2bf(l2w[gid - 4096]);
    } else if (gid < 12288) {
      int tt = gid - 8192, o = tt >> 6, m = tt & 63;
      float s = 0.f;
      for (int c = 0; c < 64; c++) s = fmaf(l1w[o * 64 + c], l1w[c * 64 + m], s);
      stack4[gid] = f2bf(s);
    } else if (gid < 16384) {
      int tt = gid - 12288, o = tt >> 6, m = tt & 63;
      float s = 0.f;
      for (int c = 0; c < 64; c++) s = fmaf(l2w[o * 64 + c], l2w[c * 64 + m], s);
      stack4[gid] = f2bf(s);
    } else if (gid < 16512) {
      int r = gid - 16384;
      rb2ext[r] = (r < 64) ? 0.f : l2b[r - 64];
    } else if (gid < 16640) {
      int r = gid - 16512;
      float v = 0.f;
      if (r >= 64) { int o = r - 64; for (int c = 0; c < 64; c++) v = fmaf(l2w[o * 64 + c], l2b[c], v); }
      rl2ext[r] = v;
    } else if (gid < 20736) {
      uaiw_bf[gid - 16640] = f2bf(uaiw[gid - 16640]);
    } else if (gid < 24832) {
      int idx = gid - 20736;                 // idx = k*64 + e
      int k = idx >> 6, e = idx & 63;
      attwT_bf[idx] = f2bf(attW[e * 64 + k]);
    } else if (gid < 24960) {
      int c = gid - 24832;                   // w1[c], w2[c]: attW row-dot with a1/a2
      int cc = c & 63, which = c >> 6;
      float s = 0.f;
      for (int k = 0; k < 64; k++) s = fmaf(attW[cc * 64 + k], atta[which * 64 + k], s);
      w12[c] = s;
    }
  } else if (bid < 4194) {
    const long long i = (long long)(bid - 98) * 256 + t;
    emb2w_bf[i] = f2bf(emb2w[i]);
  } else if (bid < 5218) {
    const int be = bid - 4194;
    const int b = be >> 6, e = be & 63;
    float* w = sm;
    if (t < CI) w[t] = ew[e * CI + t];
    __syncthreads();
    const float bias = eb[e];
    const float* xb = x + (long long)b * CI * NI;
    u16* outp = h0a + (long long)be * NI;
    for (int n = t; n < NI; n += 256) {
      float a = bias;
#pragma unroll
      for (int c = 0; c < CI; c++) a = fmaf(xb[c * NI + n], w[c], a);
      outp[n] = f2bf(lrelu01(a));
    }
  } else if (bid < 9314) {
    const long long idx = (long long)(bid - 5218) * 256 + t;
    const int m = (int)(idx >> 10), j = (int)(idx & 1023);
    const float* d = dsum + NI;
    float v = (gd[NN2 + idx] + (m == j ? 1.f : 0.f)) * d[m] * d[j];
    g2t[idx] = f2bf(v);
  } else if (bid < 10338) {
    const int sub = bid - 9314;
    const int bx = (sub & 31) * 32, by = (sub >> 5) * 32;
    const int lx = t & 31, ly = t >> 5;  // 32x8
    float* tile = sm;                    // 32x33
    for (int yy = ly; yy < 32; yy += 8)
      tile[yy * 33 + lx] = gd[(long long)(by + yy) * NI + bx + lx];
    __syncthreads();
    for (int yy = ly; yy < 32; yy += 8) {
      const int i = bx + yy, j = by + lx;
      float v = (tile[lx * 33 + yy] + (i == j ? 1.f : 0.f)) * dsum[i] * dsum[j];
      g1[(long long)i * NI + j] = f2bf(v);
    }
  } else {
    const int n = bid - 10338;
    float s = 0.f;
    for (int i = t; i < NI; i += 256) s = fmaf(gd[(long long)n * NI + i], dsum[i], s);
    float* red = sm;
    red[t] = s; __syncthreads();
    for (int st = 128; st > 0; st >>= 1) {
      if (t < st) red[t] += red[t + st];
      __syncthreads();
    }
    if (t == 0) cs1[n] = dsum[n] * (red[0] + dsum[n]);
  }
}

// cs2[m] = colsum g2; v2[m] = (cs1 @ g2)[m]
__global__ __launch_bounds__(256) void csv2_kernel(const float* __restrict__ gd1,
                                                   const float* __restrict__ d,
                                                   const float* __restrict__ cs1,
                                                   float* __restrict__ cs2,
                                                   float* __restrict__ v2)
{
  const int m = blockIdx.x;
  float s = 0.f, sv = 0.f;
  for (int n = threadIdx.x; n < NI; n += 256) {
    float g = gd1[(long long)m * NI + n] * d[n];
    s += g;
    sv = fmaf(g, cs1[n], sv);
  }
  __shared__ float r1[256], r2[256];
  r1[threadIdx.x] = s; r2[threadIdx.x] = sv; __syncthreads();
  for (int st = 128; st > 0; st >>= 1) {
    if (threadIdx.x < st) { r1[threadIdx.x] += r1[threadIdx.x + st]; r2[threadIdx.x] += r2[threadIdx.x + st]; }
    __syncthreads();
  }
  if (threadIdx.x == 0) {
    cs2[m] = d[m] * (r1[0] + d[m]);
    v2[m] = d[m] * (r2[0] + d[m] * cs1[m]);
  }
}

// invZatt[b][i] = 1 / sum_j exp(lrelu(s1_i+s2_j) - lrelu(s1_i+s2max)). Wave per row.
__global__ __launch_bounds__(256) void att_z(const float* __restrict__ s1,
                                             const float* __restrict__ s2,
                                             const unsigned* __restrict__ s2mU,
                                             float* __restrict__ invZatt)
{
  const int b = blockIdx.y;
  const int wid = threadIdx.x >> 6, lane = threadIdx.x & 63;
  const int i = blockIdx.x * 4 + wid;
  const float s1i = s1[(long long)b * NI + i];
  const float m = lrelu01(s1i + funkey(s2mU[b]));
  const float* s2b = s2 + (long long)b * NI;
  float lsum = 0.f;
#pragma unroll
  for (int it = 0; it < 4; it++) {
    const int j0 = it * 256 + lane * 4;
    float4 sv = *(const float4*)(s2b + j0);
    lsum += __expf(lrelu01(s1i + sv.x) - m) + __expf(lrelu01(s1i + sv.y) - m)
          + __expf(lrelu01(s1i + sv.z) - m) + __expf(lrelu01(s1i + sv.w) - m);
  }
  for (int off = 1; off < 64; off <<= 1) lsum += __shfl_xor(lsum, off);
  if (lane == 0) invZatt[(long long)b * NI + i] = 1.f / lsum;
}

// cc[b][m] = sum_i W[b][m][i]/Zgl[b][i] + cs2[m]. One wave per row.
__global__ __launch_bounds__(256) void cc_kernel(const u16* __restrict__ W,
                                                 const float* __restrict__ Zgl,
                                                 const float* __restrict__ cs2,
                                                 float* __restrict__ cc)
{
  const int b = blockIdx.y;
  const int wid = threadIdx.x >> 6, lane = threadIdx.x & 63;
  const int m = blockIdx.x * 4 + wid;
  const u16* row = W + (long long)b * NN2 + (long long)m * NI;
  const float* zz = Zgl + (long long)b * NI;
  float s = 0.f;
#pragma unroll
  for (int it = 0; it < 4; it++) {
    const int j0 = it * 256 + lane * 4;
    uint2 pk = *(const uint2*)(row + j0);
    float4 zv = *(const float4*)(zz + j0);
    s += bf2f((u16)(pk.x & 0xffff)) / zv.x + bf2f((u16)(pk.x >> 16)) / zv.y
       + bf2f((u16)(pk.y & 0xffff)) / zv.z + bf2f((u16)(pk.y >> 16)) / zv.w;
  }
  for (int off = 1; off < 64; off <<= 1) s += __shfl_xor(s, off);
  if (lane == 0) cc[(long long)b * NI + m] = s + cs2[m];
}

// ---- LayerNorm apply + GELU + final gating, 64x64 tiles, LDS transpose of xu(bf16) ----
__global__ __launch_bounds__(256) void ln_final_t(const float* __restrict__ T,
                                                  const float* __restrict__ stats,
                                                  const float* __restrict__ lnw,
                                                  const float* __restrict__ lnb,
                                                  const float* __restrict__ ct,
                                                  const u16* __restrict__ xuT,
                                                  float* __restrict__ outp)
{
  __shared__ float xs[64 * 65];
  const int blk = blockIdx.x;
  const int b = blk >> 4;
  const int n0 = (blk & 15) << 6;
  const int t = threadIdx.x;
  const int tc = t & 63, tr = t >> 6;
#pragma unroll
  for (int i = 0; i < 16; i++) {
    int nn = i * 4 + tr;
    xs[tc * 65 + nn] = bf2f(xuT[((long long)b << 16) + (long long)(n0 + nn) * 64 + tc]);
  }
  __syncthreads();
  const float inv_n = 1.f / 65536.f;
  const float m0 = stats[b * 2] * inv_n;
  const float m1 = stats[b * 2 + 1] * inv_n;
  const float rs0 = rsqrtf(fmaxf(stats[32 + b * 2] * inv_n - m0 * m0, 0.f) + 1e-5f);
  const float rs1 = rsqrtf(fmaxf(stats[32 + b * 2 + 1] * inv_n - m1 * m1, 0.f) + 1e-5f);
#pragma unroll
  for (int j = 0; j < 16; j++) {
    const int c = j * 4 + tr;
    const int n = n0 + tc;
    const int rem = c * NI + n;
    const long long toff = (long long)b * S2 + rem;
    const float t0 = T[toff];
    const float t1 = T[toff + S1];
    const float w = lnw[rem], bb = lnb[rem];
    const float xn = (t0 - m0) * rs0 * w + bb;
    float ft = (t1 - m1) * rs1 * w + bb;
    ft = 0.5f * ft * (1.f + erff(ft * 0.70710678118654752f));
    const float u = xs[c * 65 + tc];
    const long long oidx = ((long long)b << 16) + rem;
    const float cn = fmaf(ft, ct[oidx] - xn, xn);
    const float el = cn > 0.f ? cn : expm1f(cn);
    outp[oidx] = fmaf(ft, el - u, u);
    outp[BCN + oidx] = cn;
  }
}

extern "C" void kernel_launch(void* const* d_in, const int* in_sizes, int n_in,
                              void* d_out, int out_size, void* d_ws, size_t ws_size,
                              hipStream_t stream)
{
  (void)in_sizes; (void)n_in; (void)out_size; (void)ws_size;
  const float* x      = (const float*)d_in[0];
  const float* ct     = (const float*)d_in[1];
  const float* gdata  = (const float*)d_in[2];
  const float* emb_w  = (const float*)d_in[3];
  const float* emb_b  = (const float*)d_in[4];
  const float* emb2_w = (const float*)d_in[5];
  const float* emb2_b = (const float*)d_in[6];
  const float* att_W  = (const float*)d_in[7];
  const float* att_a  = (const float*)d_in[8];
  // d_in[9] att_GL unused: softmax(relu(GL GL^T)) > 0 everywhere -> mask is a no-op
  const float* uai_w  = (const float*)d_in[10];
  const float* uai_b  = (const float*)d_in[11];
  const float* lin1_w = (const float*)d_in[12];
  const float* lin2_w = (const float*)d_in[13];
  const float* lin2_b = (const float*)d_in[14];
  const float* ln_w   = (const float*)d_in[15];
  const float* ln_b   = (const float*)d_in[16];
  float* outp = (float*)d_out;

  float* ws = (float*)d_ws;
  long long o = 0;
  auto af = [&](long long n) { float* p = ws + o; o += (n + 63) & ~63LL; return p; };
  auto au = [&](long long n) { return (u16*)af((n + 1) / 2); };

  float* Tacc    = af(S2 * BATCH);
  float* s1      = af(BNv);
  float* s2      = af(BNv);
  float* invZatt = af(BNv);
  float* dsum    = af(2 * NI);
  float* cs1v    = af(NI);
  float* cs2v    = af(NI);
  float* v2v     = af(NI);
  float* ccv     = af(BNv);
  float* rb2ext  = af(128);
  float* rl2ext  = af(128);
  float* w12     = af(128);
  // contiguous zero-init region: Zgl, sqv, stats(64), s2mU(16)
  float* zeroreg = af(2 * BNv + 80);
  float* Zgl     = zeroreg;
  float* sqv     = zeroreg + BNv;
  float* stats   = zeroreg + 2 * BNv;
  unsigned* s2mU = (unsigned*)(stats + 64);
  u16* emb2w_bf  = au(NN2);
  u16* h0a_bf    = au(S1 * BATCH);
  u16* h0Tb      = au(S1 * BATCH);   // [b][n][e]
  u16* hTb       = au(S1 * BATCH);   // [b][c][n]
  u16* xattb     = au(S1 * BATCH);   // [b][n][c]
  u16* xuaiTb    = au(S1 * BATCH);   // [b][n][c]
  u16* g1b       = au(NN2);
  u16* g2tb      = au(NN2);
  u16* G12b      = au(NN2);
  u16* Abig      = au((long long)BATCH * 128 * 2048);
  u16* stack4    = au(256 * 64);
  u16* uaiw_bf   = au(CE * CE);
  u16* attwT_bf  = au(CE * CE);
  u16* bigW      = au(BNN);  // 32 MB: gram W only (att-p is computed on the fly now)

  hipMemsetAsync(zeroreg, 0, (2 * BNv + 80) * sizeof(float), stream);

  lap_rowsum<<<2 * NI, 256, 0, stream>>>(gdata, dsum);

  mega_prep<<<11362, 256, 0, stream>>>(
      lin1_w, lin2_w, lin2_b, uai_w, att_W, att_a,
      stack4, rb2ext, rl2ext, uaiw_bf, attwT_bf, w12,
      emb2_w, emb2w_bf, x, emb_w, emb_b, h0a_bf,
      gdata, dsum, g2tb, g1b, cs1v);

  csv2_kernel<<<NI, 256, 0, stream>>>(gdata + NN2, dsum + NI, cs1v, cs2v, v2v);

  // G12t = (g1@g2)^T = TN(A=g2t, Bt=g1)
  mgemm<64, 64, 6><<<dim3(16, 16, 1), 256, 0, stream>>>(
      g2tb, g1b, nullptr, NI, NI, NI, NI, 0, 0,
      nullptr, G12b, NI, 0, nullptr, nullptr, nullptr, nullptr, nullptr);

  // h0T[b][m][e] = emb2w @ h0a^T + emb2_b, fused s1/s2/s2max epilogue
  mgemm<64, 64, 11><<<dim3(1, 16, BATCH), 256, 0, stream>>>(
      emb2w_bf, h0a_bf, (const u16*)s2mU, NI, NI, NI, NI, 0, S1,
      s1, h0Tb, CE, S1, w12, w12 + 64, emb2_b, nullptr, s2);

  att_z<<<dim3(NI / 4, BATCH), 256, 0, stream>>>(s1, s2, s2mU, invZatt);

  // hT[b][c][n] = attW^T @ h0T^T  (K=64, bf16)
  mgemm<64, 64, 6><<<dim3(16, 1, BATCH), 256, 0, stream>>>(
      attwT_bf, h0Tb, nullptr, CE, CE, CE, CE, 0, S1,
      nullptr, hTb, NI, S1, nullptr, nullptr, nullptr, nullptr, nullptr);

  // x_att = relu((p@h)*invZ), p computed on the fly in A-staging -> bf16 [b][n][c]
  mgemm<64, 64, 10><<<dim3(1, 16, BATCH), 256, 0, stream>>>(
      hTb, hTb, nullptr, NI, NI, NI, NI, 0, S1,
      nullptr, xattb, CE, S1, invZatt, s1, s2, nullptr, (float*)s2mU);

  // x_uaiT = x_att @ uai_w^T + uai_b (bf16, rowsq atomics into sqv)
  mgemm<64, 64, 2><<<dim3(1, 16, BATCH), 256, 0, stream>>>(
      xattb, uaiw_bf, nullptr, CE, CE, CE, CE, S1, 0,
      nullptr, xuaiTb, CE, S1, uai_b, nullptr, nullptr, nullptr, sqv);

  // gram/gl weights (128x128 tiles; exp epilogue; rowsums into Zgl)
  mgemm<128, 128, 3><<<dim3(8, 8, BATCH), 256, 0, stream>>>(
      xuaiTb, xuaiTb, nullptr, CE, CE, CE, CE, S1, S1,
      nullptr, bigW, NI, NN2, sqv, nullptr, nullptr, nullptr, Zgl);

  cc_kernel<<<dim3(NI / 4, BATCH), 256, 0, stream>>>(bigW, Zgl, cs2v, ccv);

  // Abig = [[L1u/Z | L1L1u],[L2u/Z | L2L2u]] bf16
  mgemm<64, 64, 4><<<dim3(16, 4, BATCH), 256, 0, stream>>>(
      stack4, xuaiTb, nullptr, CE, CE, CE, CE, 0, S1,
      nullptr, Abig, 0, (long long)128 * 2048, Zgl, nullptr, nullptr, nullptr, nullptr);

  // fused: Tacc = Abig @ [W ; G12t] + b2 (x) cc + (L2 b2) (x) v2, + LN-stats atomics
  mgemm<64, 128, 5><<<dim3(8, 2, BATCH), 256, 0, stream>>>(
      Abig, bigW, G12b, NI, 2 * NI, 2048, NI, (long long)128 * 2048, NN2,
      Tacc, nullptr, NI, S2, ccv, v2v, rb2ext, rl2ext, stats);

  ln_final_t<<<256, 256, 0, stream>>>(Tacc, stats, ln_w, ln_b, ct, xuaiTb, outp);
}